// Round 1
// baseline (255.018 us; speedup 1.0000x reference)
//
#include <hip/hip_runtime.h>

#define TSEQ 1024

__device__ __forceinline__ float fast_sigmoid(float x) {
    // 1 / (1 + exp(-x)) = 1 / (1 + exp2(-x*log2e)); stable at +/-inf
    float e = __builtin_amdgcn_exp2f(-1.4426950408889634f * x);
    return __builtin_amdgcn_rcpf(1.0f + e);
}

__device__ __forceinline__ float fast_tanh(float x) {
    // tanh(x) = 1 - 2/(1 + exp(2x)); exp(2x) = exp2(2*log2e*x); stable at +/-inf
    float e = __builtin_amdgcn_exp2f(2.8853900817779268f * x);
    return 1.0f - 2.0f * __builtin_amdgcn_rcpf(1.0f + e);
}

struct Weights {
    float w1[4], u1[4], v1[16], b1[4];
    float w2[4], u2[4], v2[16], b2[4];
    float fw, fb;
};

// Process 8 timesteps from a 10x float4 register buffer (40 floats = 8 steps * 5 ch).
__device__ __forceinline__ void compute8(const float4 (&buf)[10], const Weights& W,
                                         float& h1, float& c1, float& h2, float& c2,
                                         float4* op2) {
    float arr[40];
#pragma unroll
    for (int q = 0; q < 10; q++) {
        arr[4*q+0] = buf[q].x; arr[4*q+1] = buf[q].y;
        arr[4*q+2] = buf[q].z; arr[4*q+3] = buf[q].w;
    }
    float res[8];
#pragma unroll
    for (int s = 0; s < 8; s++) {
        const float a0 = arr[5*s+0], a1 = arr[5*s+1], a2 = arr[5*s+2], a3 = arr[5*s+3];
        const float xx = arr[5*s+4];
        float g[4];
        // layer 1 gates: x*W1 + h1*U1 + w@V1 + b1   (V row-major [4][4], col = gate)
#pragma unroll
        for (int k = 0; k < 4; k++) {
            float t = W.b1[k];
            t = fmaf(a0, W.v1[0*4+k], t);
            t = fmaf(a1, W.v1[1*4+k], t);
            t = fmaf(a2, W.v1[2*4+k], t);
            t = fmaf(a3, W.v1[3*4+k], t);
            t = fmaf(xx, W.w1[k], t);
            t = fmaf(h1, W.u1[k], t);
            g[k] = t;
        }
        float i1 = fast_sigmoid(g[0]);
        float f1 = fast_sigmoid(g[1]);
        float gg1 = fast_tanh(g[2]);
        float o1 = fast_sigmoid(g[3]);
        c1 = fmaf(f1, c1, i1 * gg1);
        h1 = o1 * fast_tanh(c1);
        // layer 2 gates: h1*W2 + h2*U2 + w@V2 + b2
#pragma unroll
        for (int k = 0; k < 4; k++) {
            float t = W.b2[k];
            t = fmaf(a0, W.v2[0*4+k], t);
            t = fmaf(a1, W.v2[1*4+k], t);
            t = fmaf(a2, W.v2[2*4+k], t);
            t = fmaf(a3, W.v2[3*4+k], t);
            t = fmaf(h1, W.w2[k], t);
            t = fmaf(h2, W.u2[k], t);
            g[k] = t;
        }
        float i2 = fast_sigmoid(g[0]);
        float f2 = fast_sigmoid(g[1]);
        float gg2 = fast_tanh(g[2]);
        float o2 = fast_sigmoid(g[3]);
        c2 = fmaf(f2, c2, i2 * gg2);
        h2 = o2 * fast_tanh(c2);
        res[s] = fmaf(h2, W.fw, W.fb);
    }
    op2[0] = make_float4(res[0], res[1], res[2], res[3]);
    op2[1] = make_float4(res[4], res[5], res[6], res[7]);
}

__global__ __launch_bounds__(64, 1) void pew_lstm_kernel(
    const float* __restrict__ input,
    const float* __restrict__ W1, const float* __restrict__ U1,
    const float* __restrict__ V1, const float* __restrict__ b1,
    const float* __restrict__ W2, const float* __restrict__ U2,
    const float* __restrict__ V2, const float* __restrict__ b2,
    const float* __restrict__ fcW, const float* __restrict__ fcb,
    float* __restrict__ out, int B)
{
    int b = blockIdx.x * 64 + threadIdx.x;
    if (b >= B) return;

    Weights W;
#pragma unroll
    for (int k = 0; k < 4; k++) {
        W.w1[k] = W1[k]; W.u1[k] = U1[k]; W.b1[k] = b1[k];
        W.w2[k] = W2[k]; W.u2[k] = U2[k]; W.b2[k] = b2[k];
    }
#pragma unroll
    for (int k = 0; k < 16; k++) { W.v1[k] = V1[k]; W.v2[k] = V2[k]; }
    W.fw = fcW[0]; W.fb = fcb[0];

    // Each sequence row: 1024*5 floats = 20480 bytes, 16B-aligned.
    const float4* __restrict__ p = reinterpret_cast<const float4*>(input + (size_t)b * (TSEQ * 5));
    float4* __restrict__ op = reinterpret_cast<float4*>(out + (size_t)b * TSEQ);

    float h1 = 0.f, c1 = 0.f, h2 = 0.f, c2 = 0.f;

    float4 bufA[10], bufB[10];
#pragma unroll
    for (int q = 0; q < 10; q++) bufA[q] = p[q];

    // 128 chunks of 8 steps; double-buffered prefetch (loads issued ~1 chunk
    // (~1200 cy of compute) ahead of use -> HBM latency hidden).
#pragma unroll 1
    for (int ch = 0; ch < 128; ch += 2) {
#pragma unroll
        for (int q = 0; q < 10; q++) bufB[q] = p[(ch + 1) * 10 + q];
        compute8(bufA, W, h1, c1, h2, c2, op + 2 * ch);
        if (ch + 2 < 128) {
#pragma unroll
            for (int q = 0; q < 10; q++) bufA[q] = p[(ch + 2) * 10 + q];
        }
        compute8(bufB, W, h1, c1, h2, c2, op + 2 * (ch + 1));
    }
}

extern "C" void kernel_launch(void* const* d_in, const int* in_sizes, int n_in,
                              void* d_out, int out_size, void* d_ws, size_t ws_size,
                              hipStream_t stream) {
    const float* input = (const float*)d_in[0];
    const float* W1 = (const float*)d_in[1];
    const float* U1 = (const float*)d_in[2];
    const float* V1 = (const float*)d_in[3];
    const float* b1 = (const float*)d_in[4];
    const float* W2 = (const float*)d_in[5];
    const float* U2 = (const float*)d_in[6];
    const float* V2 = (const float*)d_in[7];
    const float* b2 = (const float*)d_in[8];
    const float* fcW = (const float*)d_in[9];
    const float* fcb = (const float*)d_in[10];
    float* out = (float*)d_out;

    int B = in_sizes[0] / (TSEQ * 5);
    int blocks = (B + 63) / 64;
    hipLaunchKernelGGL(pew_lstm_kernel, dim3(blocks), dim3(64), 0, stream,
                       input, W1, U1, V1, b1, W2, U2, V2, b2, fcW, fcb, out, B);
}

// Round 3
// 125.220 us; speedup vs baseline: 2.0366x; 2.0366x over previous
//
#include <hip/hip_runtime.h>

#define TSEQ 1024
#define LOG2E 1.4426950408889634f

// DPP quad_perm broadcast: CTRL=0x00/0x55/0xAA/0xFF = broadcast lane 0/1/2/3 of quad.
template<int CTRL>
__device__ __forceinline__ float dppf(float v) {
    int r = __builtin_amdgcn_update_dpp(0, __float_as_int(v), CTRL, 0xF, 0xF, true);
    return __int_as_float(r);
}

// Direction-proof lane swap: lane <-> lane^4 (within 32-lane halves; 8-lane
// groups never straddle the boundary). offset = (xor<<10)|(or<<5)|and = 0x101F.
__device__ __forceinline__ float swap4(float v) {
    return __int_as_float(__builtin_amdgcn_ds_swizzle(__float_as_int(v), 0x101F));
}

// compile-time component pick from a float4 buffer (I is constant after unroll)
#define AV(B, I) ((I) % 4 == 0 ? (B)[(I)/4].x : (I) % 4 == 1 ? (B)[(I)/4].y \
                 : (I) % 4 == 2 ? (B)[(I)/4].z : (B)[(I)/4].w)

struct LaneW {
    float vb, v0, v1, v2, v3, wc, uc;   // bias, V[0..3][g], W[g], U[g] (layer-selected)
    float m_act, s0a, s1a;              // activation: a = s0 + s1*rcp(1+exp2(m*z))
    float fw, fb;
    bool isl2;
};

// One fused step. Layer-1 lanes (even quads) process step tau; layer-2 lanes
// (odd quads) process step tau-1 using zvp (their own previous weather-dot)
// and hx (h1(tau-1), handed over by lane-swap at the end of the previous call).
__device__ __forceinline__ float lstm_step(
    float a0, float a1, float a2, float a3, float xv,
    const LaneW& w, float& h, float& c, float& hx, float& zvp)
{
    float zv = fmaf(a0, w.v0, w.vb);          // weather dot for CURRENT tau (all lanes)
    zv = fmaf(a1, w.v1, zv);
    zv = fmaf(a2, w.v2, zv);
    zv = fmaf(a3, w.v3, zv);
    float zvu = w.isl2 ? zvp : zv;            // layer2 consumes previous step's dot
    float xop = w.isl2 ? hx  : xv;            // layer2 "x" input is h1(tau-1)
    zvp = zv;
    float z = fmaf(xop, w.wc, zvu);
    z = fmaf(h, w.uc, z);
    // uniform activation: sigmoid (g!=2) or tanh (g==2) via per-lane consts
    float e = __builtin_amdgcn_exp2f(w.m_act * z);
    float r = __builtin_amdgcn_rcpf(1.0f + e);
    float a = fmaf(w.s1a, r, w.s0a);
    float vi = dppf<0x00>(a);                 // gate i from lane 0 of quad
    float vf = dppf<0x55>(a);                 // f from lane 1
    float vg = dppf<0xAA>(a);                 // g from lane 2
    float vo = dppf<0xFF>(a);                 // o from lane 3
    c = fmaf(vf, c, vi * vg);                 // replicated across quad
    float e2 = __builtin_amdgcn_exp2f((2.0f * LOG2E) * c);
    float r2 = __builtin_amdgcn_rcpf(1.0f + e2);
    float t = vo * r2;
    h = fmaf(t, -2.0f, vo);                   // h = o * tanh(c)
    hx = swap4(h);                            // hand h1(tau) to layer-2 quad (lane^4)
    return fmaf(h, w.fw, w.fb);               // FC (meaningful on layer-2 lanes)
}

__global__ __launch_bounds__(256, 1) void pew_lstm_kernel(
    const float* __restrict__ input,
    const float* __restrict__ W1, const float* __restrict__ U1,
    const float* __restrict__ V1, const float* __restrict__ b1,
    const float* __restrict__ W2, const float* __restrict__ U2,
    const float* __restrict__ V2, const float* __restrict__ b2,
    const float* __restrict__ fcW, const float* __restrict__ fcb,
    float* __restrict__ out, int B)
{
    const int lane = threadIdx.x & 63;
    const int wave = (blockIdx.x * blockDim.x + threadIdx.x) >> 6;
    const int seq  = wave * 8 + (lane >> 3);
    if (seq >= B) return;
    const bool isl2 = (lane & 4) != 0;
    const int  g    = lane & 3;

    LaneW w;
    w.isl2 = isl2;
    const float* Wx = isl2 ? W2 : W1;
    const float* Ux = isl2 ? U2 : U1;
    const float* Vx = isl2 ? V2 : V1;
    const float* bx = isl2 ? b2 : b1;
    w.wc = Wx[g]; w.uc = Ux[g]; w.vb = bx[g];
    w.v0 = Vx[g]; w.v1 = Vx[4 + g]; w.v2 = Vx[8 + g]; w.v3 = Vx[12 + g];
    const bool istanh = (g == 2);
    w.m_act = istanh ? (2.0f * LOG2E) : (-LOG2E);
    w.s0a   = istanh ? 1.0f : 0.0f;
    w.s1a   = istanh ? -2.0f : 1.0f;
    w.fw = fcW[0]; w.fb = fcb[0];

    // All 8 lanes of a sequence load the same row (coalescer dedupes).
    const float4* __restrict__ p  = reinterpret_cast<const float4*>(input + (size_t)seq * (TSEQ * 5));
    float4* __restrict__       op = reinterpret_cast<float4*>(out + (size_t)seq * TSEQ);
    const bool stlane = (lane & 7) == 4;      // one layer-2 lane per sequence stores

    float4 bufA[10], bufB[10];                // 8 steps per buffer (40 floats)
#pragma unroll
    for (int q = 0; q < 10; q++) bufA[q] = p[q];
#pragma unroll
    for (int q = 0; q < 10; q++) bufB[q] = p[10 + q];

    float h = 0.f, c = 0.f, hx = 0.f, zvp = 0.f;
    float ro[16];                             // 16 results -> one 64B store burst

#pragma unroll 1
    for (int m = 0; m < 64; m++) {
        // chunk 2m: steps tau = 16m .. 16m+7 from bufA
#pragma unroll
        for (int j = 0; j < 8; j++) {
            float res = lstm_step(AV(bufA,5*j+0), AV(bufA,5*j+1), AV(bufA,5*j+2),
                                  AV(bufA,5*j+3), AV(bufA,5*j+4), w, h, c, hx, zvp);
            if (j == 0) {
                ro[15] = res;                  // u = 16m-1
                if (m > 0 && stlane) {         // flush u = 16(m-1) .. 16m-1
                    int ob = 4 * (m - 1);
                    op[ob+0] = make_float4(ro[0], ro[1], ro[2], ro[3]);
                    op[ob+1] = make_float4(ro[4], ro[5], ro[6], ro[7]);
                    op[ob+2] = make_float4(ro[8], ro[9], ro[10], ro[11]);
                    op[ob+3] = make_float4(ro[12], ro[13], ro[14], ro[15]);
                }
            } else {
                ro[j-1] = res;                 // u = 16m + j - 1
            }
        }
        if (m < 63) {
#pragma unroll
            for (int q = 0; q < 10; q++) bufA[q] = p[(2*m + 2) * 10 + q];
        }
        // chunk 2m+1: steps tau = 16m+8 .. 16m+15 from bufB
#pragma unroll
        for (int j = 0; j < 8; j++) {
            float res = lstm_step(AV(bufB,5*j+0), AV(bufB,5*j+1), AV(bufB,5*j+2),
                                  AV(bufB,5*j+3), AV(bufB,5*j+4), w, h, c, hx, zvp);
            ro[7 + j] = res;                   // u = 16m + 7 + j
        }
        if (m < 63) {
#pragma unroll
            for (int q = 0; q < 10; q++) bufB[q] = p[(2*m + 3) * 10 + q];
        }
    }
    // epilogue: layer-2 finishes u = 1023 (consumes zv(1023) and hx = h1(1023))
    {
        float res = lstm_step(AV(bufB,35), AV(bufB,36), AV(bufB,37),
                              AV(bufB,38), AV(bufB,39), w, h, c, hx, zvp);
        ro[15] = res;
        if (stlane) {
            op[252] = make_float4(ro[0], ro[1], ro[2], ro[3]);
            op[253] = make_float4(ro[4], ro[5], ro[6], ro[7]);
            op[254] = make_float4(ro[8], ro[9], ro[10], ro[11]);
            op[255] = make_float4(ro[12], ro[13], ro[14], ro[15]);
        }
    }
}

extern "C" void kernel_launch(void* const* d_in, const int* in_sizes, int n_in,
                              void* d_out, int out_size, void* d_ws, size_t ws_size,
                              hipStream_t stream) {
    const float* input = (const float*)d_in[0];
    const float* W1 = (const float*)d_in[1];
    const float* U1 = (const float*)d_in[2];
    const float* V1 = (const float*)d_in[3];
    const float* b1 = (const float*)d_in[4];
    const float* W2 = (const float*)d_in[5];
    const float* U2 = (const float*)d_in[6];
    const float* V2 = (const float*)d_in[7];
    const float* b2 = (const float*)d_in[8];
    const float* fcW = (const float*)d_in[9];
    const float* fcb = (const float*)d_in[10];
    float* out = (float*)d_out;

    int B = in_sizes[0] / (TSEQ * 5);
    int threads_total = B * 8;                 // 8 lanes per sequence
    int blocks = (threads_total + 255) / 256;  // 256 blocks at B=8192 -> 1 per CU
    hipLaunchKernelGGL(pew_lstm_kernel, dim3(blocks), dim3(256), 0, stream,
                       input, W1, U1, V1, b1, W2, U2, V2, b2, fcW, fcb, out, B);
}

// Round 4
// 103.941 us; speedup vs baseline: 2.4535x; 1.2047x over previous
//
#include <hip/hip_runtime.h>

#define TSEQ 1024
#define LOG2E 1.4426950408889634f

// DPP: CTRL=0x00/0x55/0xAA/0xFF = quad_perm broadcast lane 0/1/2/3 of quad;
// CTRL=0x114 = row_shr:4 (lane i <- lane i-4 within 16-lane row; low 4 -> 0).
template<int CTRL>
__device__ __forceinline__ float dppf(float v) {
    int r = __builtin_amdgcn_update_dpp(0, __float_as_int(v), CTRL, 0xF, 0xF, true);
    return __int_as_float(r);
}

// compile-time component pick from a float4 buffer (I is constant after unroll)
#define AV(B, I) ((I) % 4 == 0 ? (B)[(I)/4].x : (I) % 4 == 1 ? (B)[(I)/4].y \
                 : (I) % 4 == 2 ? (B)[(I)/4].z : (B)[(I)/4].w)

struct LaneW {
    float vb, v0, v1, v2, v3, wc, uc;   // bias, V[0..3][g], W[g], U[g] (layer-selected)
    float m_act, s0a, s1a;              // activation: a = s0 + s1*rcp(1+exp2(m*z))
    float fw, fb;
    bool isl2;
};

// One fused step. Layer-1 lanes (even quads) process step tau; layer-2 lanes
// (odd quads) process step tau-1 using zvp (their own previous weather-dot)
// and hx (h1(tau-1), handed over by row_shr:4 at the end of the previous call).
__device__ __forceinline__ float lstm_step(
    float a0, float a1, float a2, float a3, float xv,
    const LaneW& w, float& h, float& c, float& hx, float& zvp)
{
    float zv = fmaf(a0, w.v0, w.vb);          // weather dot for CURRENT tau (all lanes)
    zv = fmaf(a1, w.v1, zv);
    zv = fmaf(a2, w.v2, zv);
    zv = fmaf(a3, w.v3, zv);
    float zvu = w.isl2 ? zvp : zv;            // layer2 consumes previous step's dot
    float xop = w.isl2 ? hx  : xv;            // layer2 "x" input is h1(tau-1)
    zvp = zv;
    float z = fmaf(xop, w.wc, zvu);
    z = fmaf(h, w.uc, z);
    // uniform activation: sigmoid (g!=2) or tanh (g==2) via per-lane consts
    float e = __builtin_amdgcn_exp2f(w.m_act * z);
    float r = __builtin_amdgcn_rcpf(1.0f + e);
    float a = fmaf(w.s1a, r, w.s0a);
    float vi = dppf<0x00>(a);                 // gate i from lane 0 of quad
    float vf = dppf<0x55>(a);                 // f from lane 1
    float vg = dppf<0xAA>(a);                 // g from lane 2
    float vo = dppf<0xFF>(a);                 // o from lane 3
    c = fmaf(vf, c, vi * vg);                 // replicated across quad
    float e2 = __builtin_amdgcn_exp2f((2.0f * LOG2E) * c);
    float r2 = __builtin_amdgcn_rcpf(1.0f + e2);
    float t = vo * r2;
    h = fmaf(t, -2.0f, vo);                   // h = o * tanh(c)
    hx = dppf<0x114>(h);                      // hand h1(tau) to layer-2 quad (i <- i-4)
    return fmaf(h, w.fw, w.fb);               // FC (meaningful on layer-2 lanes)
}

__global__ __launch_bounds__(256, 1) void pew_lstm_kernel(
    const float* __restrict__ input,
    const float* __restrict__ W1, const float* __restrict__ U1,
    const float* __restrict__ V1, const float* __restrict__ b1,
    const float* __restrict__ W2, const float* __restrict__ U2,
    const float* __restrict__ V2, const float* __restrict__ b2,
    const float* __restrict__ fcW, const float* __restrict__ fcb,
    float* __restrict__ out, int B)
{
    const int lane = threadIdx.x & 63;
    const int wave = (blockIdx.x * blockDim.x + threadIdx.x) >> 6;
    const int seq  = wave * 8 + (lane >> 3);
    if (seq >= B) return;
    const bool isl2 = (lane & 4) != 0;
    const int  g    = lane & 3;

    LaneW w;
    w.isl2 = isl2;
    const float* Wx = isl2 ? W2 : W1;
    const float* Ux = isl2 ? U2 : U1;
    const float* Vx = isl2 ? V2 : V1;
    const float* bx = isl2 ? b2 : b1;
    w.wc = Wx[g]; w.uc = Ux[g]; w.vb = bx[g];
    w.v0 = Vx[g]; w.v1 = Vx[4 + g]; w.v2 = Vx[8 + g]; w.v3 = Vx[12 + g];
    const bool istanh = (g == 2);
    w.m_act = istanh ? (2.0f * LOG2E) : (-LOG2E);
    w.s0a   = istanh ? 1.0f : 0.0f;
    w.s1a   = istanh ? -2.0f : 1.0f;
    w.fw = fcW[0]; w.fb = fcb[0];

    // All 8 lanes of a sequence load the same row (coalescer dedupes).
    const float4* __restrict__ p  = reinterpret_cast<const float4*>(input + (size_t)seq * (TSEQ * 5));
    float4* __restrict__       op = reinterpret_cast<float4*>(out + (size_t)seq * TSEQ);
    const bool stlane = (lane & 7) == 4;      // one layer-2 lane per sequence stores

    float4 bufA[10], bufB[10];                // 8 steps per buffer (40 floats)
#pragma unroll
    for (int q = 0; q < 10; q++) bufA[q] = p[q];
#pragma unroll
    for (int q = 0; q < 10; q++) bufB[q] = p[10 + q];

    float h = 0.f, c = 0.f, hx = 0.f, zvp = 0.f;
    float ro[16];                             // 16 results -> one 64B store burst

#pragma unroll 1
    for (int m = 0; m < 64; m++) {
        // chunk 2m: steps tau = 16m .. 16m+7 from bufA
#pragma unroll
        for (int j = 0; j < 8; j++) {
            float res = lstm_step(AV(bufA,5*j+0), AV(bufA,5*j+1), AV(bufA,5*j+2),
                                  AV(bufA,5*j+3), AV(bufA,5*j+4), w, h, c, hx, zvp);
            if (j == 0) {
                ro[15] = res;                  // u = 16m-1
                if (m > 0 && stlane) {         // flush u = 16(m-1) .. 16m-1
                    int ob = 4 * (m - 1);
                    op[ob+0] = make_float4(ro[0], ro[1], ro[2], ro[3]);
                    op[ob+1] = make_float4(ro[4], ro[5], ro[6], ro[7]);
                    op[ob+2] = make_float4(ro[8], ro[9], ro[10], ro[11]);
                    op[ob+3] = make_float4(ro[12], ro[13], ro[14], ro[15]);
                }
            } else {
                ro[j-1] = res;                 // u = 16m + j - 1
            }
        }
        if (m < 63) {
#pragma unroll
            for (int q = 0; q < 10; q++) bufA[q] = p[(2*m + 2) * 10 + q];
        }
        // chunk 2m+1: steps tau = 16m+8 .. 16m+15 from bufB
#pragma unroll
        for (int j = 0; j < 8; j++) {
            float res = lstm_step(AV(bufB,5*j+0), AV(bufB,5*j+1), AV(bufB,5*j+2),
                                  AV(bufB,5*j+3), AV(bufB,5*j+4), w, h, c, hx, zvp);
            ro[7 + j] = res;                   // u = 16m + 7 + j
        }
        if (m < 63) {
#pragma unroll
            for (int q = 0; q < 10; q++) bufB[q] = p[(2*m + 3) * 10 + q];
        }
    }
    // epilogue: layer-2 finishes u = 1023 (consumes zv(1023) and hx = h1(1023))
    {
        float res = lstm_step(AV(bufB,35), AV(bufB,36), AV(bufB,37),
                              AV(bufB,38), AV(bufB,39), w, h, c, hx, zvp);
        ro[15] = res;
        if (stlane) {
            op[252] = make_float4(ro[0], ro[1], ro[2], ro[3]);
            op[253] = make_float4(ro[4], ro[5], ro[6], ro[7]);
            op[254] = make_float4(ro[8], ro[9], ro[10], ro[11]);
            op[255] = make_float4(ro[12], ro[13], ro[14], ro[15]);
        }
    }
}

extern "C" void kernel_launch(void* const* d_in, const int* in_sizes, int n_in,
                              void* d_out, int out_size, void* d_ws, size_t ws_size,
                              hipStream_t stream) {
    const float* input = (const float*)d_in[0];
    const float* W1 = (const float*)d_in[1];
    const float* U1 = (const float*)d_in[2];
    const float* V1 = (const float*)d_in[3];
    const float* b1 = (const float*)d_in[4];
    const float* W2 = (const float*)d_in[5];
    const float* U2 = (const float*)d_in[6];
    const float* V2 = (const float*)d_in[7];
    const float* b2 = (const float*)d_in[8];
    const float* fcW = (const float*)d_in[9];
    const float* fcb = (const float*)d_in[10];
    float* out = (float*)d_out;

    int B = in_sizes[0] / (TSEQ * 5);
    int threads_total = B * 8;                 // 8 lanes per sequence
    int blocks = (threads_total + 255) / 256;  // 256 blocks at B=8192 -> 1 per CU
    hipLaunchKernelGGL(pew_lstm_kernel, dim3(blocks), dim3(256), 0, stream,
                       input, W1, U1, V1, b1, W2, U2, V2, b2, fcW, fcb, out, B);
}

// Round 5
// 98.195 us; speedup vs baseline: 2.5970x; 1.0585x over previous
//
#include <hip/hip_runtime.h>

#define TSEQ 1024
#define LOG2E 1.4426950408889634f

// DPP: CTRL=0x00/0x55/0xAA/0xFF = quad_perm broadcast lane 0/1/2/3 of quad;
// CTRL=0x114 = row_shr:4 (lane i <- lane i-4 within 16-lane row; low 4 -> 0).
template<int CTRL>
__device__ __forceinline__ float dppf(float v) {
    int r = __builtin_amdgcn_update_dpp(0, __float_as_int(v), CTRL, 0xF, 0xF, true);
    return __int_as_float(r);
}

// compile-time component pick from a float4 buffer (I is constant after unroll)
#define AV(B, I) ((I) % 4 == 0 ? (B)[(I)/4].x : (I) % 4 == 1 ? (B)[(I)/4].y \
                 : (I) % 4 == 2 ? (B)[(I)/4].z : (B)[(I)/4].w)

struct LaneW {
    // all gate weights pre-scaled by msc = (g==2 ? 2L : -L), folding the exp2
    // argument scale into the linear algebra (removes 1 mul from the chain).
    float vb, v0, v1, v2, v3;   // msc * (bias, V[0..3][g])
    float wc;                   // msc * W[g]   (L1: x-input weight; L2: h1 weight)
    float uc;                   // msc * U[g]
    float nuc;                  // -2 * uc              (h-folding: U'*h = U'*vo + nuc*vo*r2)
    float wsel, nwsel;          // L2: wc / -2*wc ; L1: 0 (cross-layer h1 term)
    float s0a, s1a;             // gate output transform: a = s0 + s1*r
                                //   sigma lanes: (0,1);  g lane: (2L, -4L)  -> a = 2L*tanh(z)
    float fw, fb;
    bool isl2;
};

// One fused step. L1 lanes (quads 0,2) compute step tau; L2 lanes (quads 1,3)
// compute step tau-1. h is never materialized on the chain: the state is
// (vo, r2) with h = vo*(1-2*r2); cell state C = 2L*c so exp2(C) needs no mul.
__device__ __forceinline__ float lstm_step(
    float a0, float a1, float a2, float a3, float xv,
    const LaneW& w, float& C, float& vo, float& r2, float& zvp)
{
    // ---- off-chain: weather dot (loads), base select, h-folding products ----
    float zv = fmaf(a3, w.v3, fmaf(a2, w.v2, fmaf(a1, w.v1, fmaf(a0, w.v0, w.vb))));
    float zb = w.isl2 ? zvp : fmaf(xv, w.wc, zv);   // L2 consumes prev weather dot
    zvp = zv;
    float vox = dppf<0x114>(vo);     // L1's vo(tau-1) -> L2 lanes (early, off-chain)
    float Pu  = vo  * w.uc;          // U'*vo
    float nPu = vo  * w.nuc;         // -2*U'*vo
    float Pw  = vox * w.wsel;        // L2: W2'*vo1 ; L1: 0
    float nPw = vox * w.nwsel;
    float Q   = (zb + Pu) + Pw;
    // ---- chain: z = Q + nPu*r2 + nPw*r2x ;  gates ; cell ----
    float r2x = dppf<0x114>(r2);     // L1's r2(tau-1) -> L2 lanes (+10 on chain)
    float t1  = fmaf(r2,  nPu, Q);
    float z   = fmaf(r2x, nPw, t1);
    float e   = __builtin_amdgcn_exp2f(z);
    float r   = __builtin_amdgcn_rcpf(1.0f + e);
    float a   = fmaf(w.s1a, r, w.s0a);
    float vi  = dppf<0x00>(a);
    float vf  = dppf<0x55>(a);
    float vg  = dppf<0xAA>(a);       // = 2L * g
    vo        = dppf<0xFF>(a);
    C         = fmaf(vf, C, vi * vg);   // C = 2L*c
    float E2  = __builtin_amdgcn_exp2f(C);
    r2        = __builtin_amdgcn_rcpf(1.0f + E2);
    // ---- off-chain: output h = vo*(1-2*r2), FC ----
    float h   = vo * fmaf(-2.0f, r2, 1.0f);
    return fmaf(h, w.fw, w.fb);
}

__global__ __launch_bounds__(256, 1) void pew_lstm_kernel(
    const float* __restrict__ input,
    const float* __restrict__ W1, const float* __restrict__ U1,
    const float* __restrict__ V1, const float* __restrict__ b1,
    const float* __restrict__ W2, const float* __restrict__ U2,
    const float* __restrict__ V2, const float* __restrict__ b2,
    const float* __restrict__ fcW, const float* __restrict__ fcb,
    float* __restrict__ out, int B)
{
    const int lane = threadIdx.x & 63;
    const int wave = (blockIdx.x * blockDim.x + threadIdx.x) >> 6;
    const int seq  = wave * 8 + (lane >> 3);
    if (seq >= B) return;
    const bool isl2 = (lane & 4) != 0;
    const int  g    = lane & 3;

    LaneW w;
    w.isl2 = isl2;
    const float* Wx = isl2 ? W2 : W1;
    const float* Ux = isl2 ? U2 : U1;
    const float* Vx = isl2 ? V2 : V1;
    const float* bx = isl2 ? b2 : b1;
    const bool istanh = (g == 2);
    const float msc = istanh ? (2.0f * LOG2E) : (-LOG2E);
    w.wc = msc * Wx[g]; w.uc = msc * Ux[g]; w.vb = msc * bx[g];
    w.v0 = msc * Vx[g]; w.v1 = msc * Vx[4 + g];
    w.v2 = msc * Vx[8 + g]; w.v3 = msc * Vx[12 + g];
    w.nuc   = -2.0f * w.uc;
    w.wsel  = isl2 ? w.wc : 0.0f;
    w.nwsel = -2.0f * w.wsel;
    w.s0a   = istanh ? (2.0f * LOG2E) : 0.0f;
    w.s1a   = istanh ? (-4.0f * LOG2E) : 1.0f;
    w.fw = fcW[0]; w.fb = fcb[0];

    const float4* __restrict__ p  = reinterpret_cast<const float4*>(input + (size_t)seq * (TSEQ * 5));
    float4* __restrict__       op = reinterpret_cast<float4*>(out + (size_t)seq * TSEQ);
    const bool stlane = (lane & 7) == 4;      // one layer-2 lane per sequence stores

    float4 bufA[10], bufB[10];                // 8 steps per buffer (40 floats)
#pragma unroll
    for (int q = 0; q < 10; q++) bufA[q] = p[q];
#pragma unroll
    for (int q = 0; q < 10; q++) bufB[q] = p[10 + q];

    // state: h encoded as vo*(1-2*r2); init h=0 via vo=0; C=2L*c=0.
    float C = 0.f, vo = 0.f, r2 = 0.5f, zvp = 0.f;
    float ro[16];                             // 16 results -> one 64B store burst

#pragma unroll 1
    for (int m = 0; m < 64; m++) {
        // chunk 2m: steps tau = 16m .. 16m+7 from bufA
#pragma unroll
        for (int j = 0; j < 8; j++) {
            float res = lstm_step(AV(bufA,5*j+0), AV(bufA,5*j+1), AV(bufA,5*j+2),
                                  AV(bufA,5*j+3), AV(bufA,5*j+4), w, C, vo, r2, zvp);
            if (j == 0) {
                ro[15] = res;                  // u = 16m-1
                if (m > 0 && stlane) {         // flush u = 16(m-1) .. 16m-1
                    int ob = 4 * (m - 1);
                    op[ob+0] = make_float4(ro[0], ro[1], ro[2], ro[3]);
                    op[ob+1] = make_float4(ro[4], ro[5], ro[6], ro[7]);
                    op[ob+2] = make_float4(ro[8], ro[9], ro[10], ro[11]);
                    op[ob+3] = make_float4(ro[12], ro[13], ro[14], ro[15]);
                }
            } else {
                ro[j-1] = res;                 // u = 16m + j - 1
            }
        }
        if (m < 63) {
#pragma unroll
            for (int q = 0; q < 10; q++) bufA[q] = p[(2*m + 2) * 10 + q];
        }
        // chunk 2m+1: steps tau = 16m+8 .. 16m+15 from bufB
#pragma unroll
        for (int j = 0; j < 8; j++) {
            float res = lstm_step(AV(bufB,5*j+0), AV(bufB,5*j+1), AV(bufB,5*j+2),
                                  AV(bufB,5*j+3), AV(bufB,5*j+4), w, C, vo, r2, zvp);
            ro[7 + j] = res;                   // u = 16m + 7 + j
        }
        if (m < 63) {
#pragma unroll
            for (int q = 0; q < 10; q++) bufB[q] = p[(2*m + 3) * 10 + q];
        }
    }
    // epilogue: layer-2 finishes u = 1023 (consumes zvp and L1's final (vo,r2))
    {
        float res = lstm_step(AV(bufB,35), AV(bufB,36), AV(bufB,37),
                              AV(bufB,38), AV(bufB,39), w, C, vo, r2, zvp);
        ro[15] = res;
        if (stlane) {
            op[252] = make_float4(ro[0], ro[1], ro[2], ro[3]);
            op[253] = make_float4(ro[4], ro[5], ro[6], ro[7]);
            op[254] = make_float4(ro[8], ro[9], ro[10], ro[11]);
            op[255] = make_float4(ro[12], ro[13], ro[14], ro[15]);
        }
    }
}

extern "C" void kernel_launch(void* const* d_in, const int* in_sizes, int n_in,
                              void* d_out, int out_size, void* d_ws, size_t ws_size,
                              hipStream_t stream) {
    const float* input = (const float*)d_in[0];
    const float* W1 = (const float*)d_in[1];
    const float* U1 = (const float*)d_in[2];
    const float* V1 = (const float*)d_in[3];
    const float* b1 = (const float*)d_in[4];
    const float* W2 = (const float*)d_in[5];
    const float* U2 = (const float*)d_in[6];
    const float* V2 = (const float*)d_in[7];
    const float* b2 = (const float*)d_in[8];
    const float* fcW = (const float*)d_in[9];
    const float* fcb = (const float*)d_in[10];
    float* out = (float*)d_out;

    int B = in_sizes[0] / (TSEQ * 5);
    int threads_total = B * 8;                 // 8 lanes per sequence
    int blocks = (threads_total + 255) / 256;  // 256 blocks at B=8192 -> 1 per CU
    hipLaunchKernelGGL(pew_lstm_kernel, dim3(blocks), dim3(256), 0, stream,
                       input, W1, U1, V1, b1, W2, U2, V2, b2, fcW, fcb, out, B);
}

// Round 6
// 95.192 us; speedup vs baseline: 2.6790x; 1.0316x over previous
//
#include <hip/hip_runtime.h>

#define TSEQ 1024
#define LOG2E 1.4426950408889634f

// DPP: CTRL=0x00/0x55/0xAA/0xFF = quad_perm broadcast lane 0/1/2/3 of quad;
// CTRL=0x114 = row_shr:4 (lane i <- lane i-4 within 16-lane row; low 4 -> 0).
template<int CTRL>
__device__ __forceinline__ float dppf(float v) {
    int r = __builtin_amdgcn_update_dpp(0, __float_as_int(v), CTRL, 0xF, 0xF, true);
    return __int_as_float(r);
}

// compile-time component pick from a float4 buffer (I is constant after unroll)
#define AV(B, I) ((I) % 4 == 0 ? (B)[(I)/4].x : (I) % 4 == 1 ? (B)[(I)/4].y \
                 : (I) % 4 == 2 ? (B)[(I)/4].z : (B)[(I)/4].w)

struct LaneW {
    // Gate pre-activations pre-scaled by msc = (g-lane ? -2L : -L) so that
    // r = rcp(1+exp2(z)) gives sigma(y) on sigma lanes and sigma(2y) on g lane.
    float vb, v0, v1, v2, v3;   // msc * (bias, V[0..3][g])
    float wcx;                  // L1: msc*W1[g] (x-input); L2: 0 (unused)
    float uc;                   // msc*U[g]   (own-h recurrent)
    float wc2;                  // L2: msc*W2[g] (h1 input); L1: 0
    float fw, fb;
    bool isl2;
};

// One fused call. L1 lanes (quads 0,2) compute step tau; L2 lanes (quads 1,3)
// compute step tau-2 (2-step lag so the cross-layer handoff is fully
// off-chain via carried regs voc/r2c). State encoding: h = vo*(2*r2-1),
// C = 2L*c (so tanh(c) = 2*rcp(1+exp2(-C)) - 1 needs no scale mul).
__device__ __forceinline__ float lstm_step2(
    float a0, float a1, float a2, float a3, float xv,
    const LaneW& w, float& C, float& vo, float& r2,
    float& zv1, float& zv2, float& voc, float& r2c)
{
    // ---- off-chain: weather dot, delay line, folded recurrent terms ----
    float zv = fmaf(a3, w.v3, fmaf(a2, w.v2, fmaf(a1, w.v1, fmaf(a0, w.v0, w.vb))));
    float zb = w.isl2 ? zv2 : fmaf(xv, w.wcx, zv);  // L2: 2-step-delayed dot
    zv2 = zv1; zv1 = zv;
    float tU = w.uc * vo;            // uc*h = ku*r2 - tU, ku = 2*tU
    float ku = tU + tU;
    float tW = w.wc2 * voc;          // cross-layer (L1: wc2=0)
    float kw = tW + tW;
    float q  = fmaf(kw, r2c, (zb - tU) - tW);
    // handoff for NEXT call: dpp of ENTRY state (off the per-step cycle)
    float nvoc = dppf<0x114>(vo);
    float nr2c = dppf<0x114>(r2);
    // ---- chain: z -> r -> C -> r2 ----
    float z  = fmaf(ku, r2, q);
    float e  = __builtin_amdgcn_exp2f(z);
    float r  = __builtin_amdgcn_rcpf(1.0f + e);
    float d3 = dppf<0x55>(r);                  // f       (sigma)
    float d2 = dppf<0xAA>(r);                  // sigma_g (tanh encoded)
    float d1 = dppf<0x00>(r);                  // i       (sigma)
    float t1 = d3 * C;
    float t2 = fmaf(4.0f * LOG2E, d2, -2.0f * LOG2E);   // = 2L*g
    vo       = dppf<0xFF>(r);                  // o (state update)
    C        = fmaf(d1, t2, t1);
    float E2 = __builtin_amdgcn_exp2f(-C);     // neg = free src modifier
    r2       = __builtin_amdgcn_rcpf(1.0f + E2);
    voc = nvoc; r2c = nr2c;
    // ---- off-chain: h, FC ----
    float tm = fmaf(2.0f, r2, -1.0f);
    float h  = vo * tm;
    return fmaf(h, w.fw, w.fb);
}

__global__ __launch_bounds__(256, 1) void pew_lstm_kernel(
    const float* __restrict__ input,
    const float* __restrict__ W1, const float* __restrict__ U1,
    const float* __restrict__ V1, const float* __restrict__ b1,
    const float* __restrict__ W2, const float* __restrict__ U2,
    const float* __restrict__ V2, const float* __restrict__ b2,
    const float* __restrict__ fcW, const float* __restrict__ fcb,
    float* __restrict__ out, int B)
{
    const int lane = threadIdx.x & 63;
    const int wave = (blockIdx.x * blockDim.x + threadIdx.x) >> 6;
    const int seq  = wave * 8 + (lane >> 3);
    if (seq >= B) return;
    const bool isl2 = (lane & 4) != 0;
    const int  g    = lane & 3;

    LaneW w;
    w.isl2 = isl2;
    const float* Wx = isl2 ? W2 : W1;
    const float* Ux = isl2 ? U2 : U1;
    const float* Vx = isl2 ? V2 : V1;
    const float* bx = isl2 ? b2 : b1;
    const bool istanh = (g == 2);
    const float msc = istanh ? (-2.0f * LOG2E) : (-LOG2E);
    w.wcx = msc * Wx[g]; w.uc = msc * Ux[g]; w.vb = msc * bx[g];
    w.v0 = msc * Vx[g]; w.v1 = msc * Vx[4 + g];
    w.v2 = msc * Vx[8 + g]; w.v3 = msc * Vx[12 + g];
    w.wc2 = isl2 ? w.wcx : 0.0f;      // L2's "x" weight acts on h1
    w.fw = fcW[0]; w.fb = fcb[0];

    const float4* __restrict__ p  = reinterpret_cast<const float4*>(input + (size_t)seq * (TSEQ * 5));
    float4* __restrict__       op = reinterpret_cast<float4*>(out + (size_t)seq * TSEQ);
    const bool stlane = (lane & 7) == 4;      // one L2 lane per sequence stores

    float4 bufA[10], bufB[10];                // 8 steps per buffer (40 floats)
#pragma unroll
    for (int q = 0; q < 10; q++) bufA[q] = p[q];
#pragma unroll
    for (int q = 0; q < 10; q++) bufB[q] = p[10 + q];

    // state: h=0 encoded as vo=0 (any r2); C=0; carries encode h1=0.
    float C = 0.f, vo = 0.f, r2 = 0.5f;
    float zv1 = 0.f, zv2 = 0.f, voc = 0.f, r2c = 0.5f;
    float ro[16];                             // u = t-2 ring; flush every 16

#pragma unroll 1
    for (int m = 0; m < 64; m++) {
        // calls t = 16m + j, j = 0..7 from bufA
#pragma unroll
        for (int j = 0; j < 8; j++) {
            float res = lstm_step2(AV(bufA,5*j+0), AV(bufA,5*j+1), AV(bufA,5*j+2),
                                   AV(bufA,5*j+3), AV(bufA,5*j+4),
                                   w, C, vo, r2, zv1, zv2, voc, r2c);
            if (m > 0 || j >= 2) ro[(j + 14) & 15] = res;   // u = 16m+j-2
            if (j == 1 && m > 0 && stlane) {                // flush block m-1
                int ob = 4 * (m - 1);
                op[ob+0] = make_float4(ro[0], ro[1], ro[2], ro[3]);
                op[ob+1] = make_float4(ro[4], ro[5], ro[6], ro[7]);
                op[ob+2] = make_float4(ro[8], ro[9], ro[10], ro[11]);
                op[ob+3] = make_float4(ro[12], ro[13], ro[14], ro[15]);
            }
        }
        if (m < 63) {
#pragma unroll
            for (int q = 0; q < 10; q++) bufA[q] = p[(2*m + 2) * 10 + q];
        }
        // calls t = 16m + 8 + j, j = 0..7 from bufB
#pragma unroll
        for (int j = 0; j < 8; j++) {
            float res = lstm_step2(AV(bufB,5*j+0), AV(bufB,5*j+1), AV(bufB,5*j+2),
                                   AV(bufB,5*j+3), AV(bufB,5*j+4),
                                   w, C, vo, r2, zv1, zv2, voc, r2c);
            ro[(j + 6) & 15] = res;                          // u = 16m+6+j
        }
        if (m < 63) {
#pragma unroll
            for (int q = 0; q < 10; q++) bufB[q] = p[(2*m + 3) * 10 + q];
        }
    }
    // epilogue: calls t = 1024, 1025 flush L2 steps 1022, 1023 (zero inputs;
    // L1 computes unused garbage; L2's weather comes from the zv delay line).
    {
        float res = lstm_step2(0.f, 0.f, 0.f, 0.f, 0.f,
                               w, C, vo, r2, zv1, zv2, voc, r2c);
        ro[14] = res;
        res = lstm_step2(0.f, 0.f, 0.f, 0.f, 0.f,
                         w, C, vo, r2, zv1, zv2, voc, r2c);
        ro[15] = res;
        if (stlane) {
            op[252] = make_float4(ro[0], ro[1], ro[2], ro[3]);
            op[253] = make_float4(ro[4], ro[5], ro[6], ro[7]);
            op[254] = make_float4(ro[8], ro[9], ro[10], ro[11]);
            op[255] = make_float4(ro[12], ro[13], ro[14], ro[15]);
        }
    }
}

extern "C" void kernel_launch(void* const* d_in, const int* in_sizes, int n_in,
                              void* d_out, int out_size, void* d_ws, size_t ws_size,
                              hipStream_t stream) {
    const float* input = (const float*)d_in[0];
    const float* W1 = (const float*)d_in[1];
    const float* U1 = (const float*)d_in[2];
    const float* V1 = (const float*)d_in[3];
    const float* b1 = (const float*)d_in[4];
    const float* W2 = (const float*)d_in[5];
    const float* U2 = (const float*)d_in[6];
    const float* V2 = (const float*)d_in[7];
    const float* b2 = (const float*)d_in[8];
    const float* fcW = (const float*)d_in[9];
    const float* fcb = (const float*)d_in[10];
    float* out = (float*)d_out;

    int B = in_sizes[0] / (TSEQ * 5);
    int threads_total = B * 8;                 // 8 lanes per sequence
    int blocks = (threads_total + 255) / 256;  // 256 blocks at B=8192 -> 1 per CU
    hipLaunchKernelGGL(pew_lstm_kernel, dim3(blocks), dim3(256), 0, stream,
                       input, W1, U1, V1, b1, W2, U2, V2, b2, fcW, fcb, out, B);
}